// Round 16
// baseline (439.953 us; speedup 1.0000x reference)
//
#include <hip/hip_runtime.h>
#include <hip/hip_bf16.h>
#include <math.h>

// Problem constants
#define BATCH 4
#define SEQ 2048
#define FEAT 1024
#define HEADS 16
#define HDIM 64
#define FF 500
#define FFP 512                 // FF padded to multiple of 128
#define ROWS (BATCH * SEQ)      // 8192
#define QKVSTR 3072             // fused q|k|v row stride
#define AQ 128                  // attn q-rows per block (8 waves x 16 rows)

typedef unsigned short ushortT;
typedef __attribute__((ext_vector_type(8))) short short8;   // 8 bf16 (4 VGPRs)
typedef __attribute__((ext_vector_type(4))) float floatx4;  // MFMA acc

#if defined(__has_builtin) && __has_builtin(__builtin_amdgcn_exp2f)
#define EXP2F(x) __builtin_amdgcn_exp2f(x)
#else
#define EXP2F(x) exp2f(x)
#endif

__device__ __forceinline__ unsigned short f2bf(float f) {
    unsigned int u = __builtin_bit_cast(unsigned int, f);
    u += 0x7fffu + ((u >> 16) & 1u);           // RNE
    return (unsigned short)(u >> 16);
}
__device__ __forceinline__ float bf2f(short b) {
    unsigned int u = ((unsigned int)(unsigned short)b) << 16;
    return __builtin_bit_cast(float, u);
}

__device__ __forceinline__ void async16(void* lds, const void* g) {
    __builtin_amdgcn_global_load_lds(
        (const __attribute__((address_space(1))) unsigned int*)g,
        (__attribute__((address_space(3))) unsigned int*)lds, 16, 0, 0);
}

// ---------------------------------------------------------------------------
// Unified prep: 6 weight transpose+convert tiles + bias concat/pad.
// ---------------------------------------------------------------------------
__global__ void prep_kernel(const float* __restrict__ Wq, const float* __restrict__ Wk,
                            const float* __restrict__ Wv, const float* __restrict__ Wo,
                            const float* __restrict__ W1, const float* __restrict__ W2,
                            const float* __restrict__ bq, const float* __restrict__ bk,
                            const float* __restrict__ bv, const float* __restrict__ b1,
                            ushortT* __restrict__ Wqkvt, ushortT* __restrict__ Wot,
                            ushortT* __restrict__ W1t, ushortT* __restrict__ W2t,
                            float* __restrict__ bqkv, float* __restrict__ b1p)
{
    const int t = blockIdx.x;
    const int tid = threadIdx.x;
    if (t == 1280) {
        for (int i = tid; i < QKVSTR; i += 256)
            bqkv[i] = (i < 1024) ? bq[i] : ((i < 2048) ? bk[i - 1024] : bv[i - 2048]);
        for (int i = tid; i < FFP; i += 256)
            b1p[i] = (i < FF) ? b1[i] : 0.0f;
        return;
    }
    const float* W; ushortT* Wt; int K, N, Kp, bx, by;
    if (t < 1024) {
        const int wi = t >> 8, lt = t & 255;
        bx = lt & 15; by = lt >> 4; K = FEAT; N = FEAT; Kp = FEAT;
        W  = (wi == 0) ? Wq : (wi == 1) ? Wk : (wi == 2) ? Wv : Wo;
        Wt = (wi == 3) ? Wot : (Wqkvt + (size_t)wi * FEAT * FEAT);
    } else if (t < 1152) {
        const int lt = t - 1024; bx = lt & 7; by = lt >> 3;
        K = FEAT; N = FF; Kp = FEAT; W = W1; Wt = W1t;
    } else {
        const int lt = t - 1152; bx = lt & 15; by = lt >> 4;
        K = FF; N = FEAT; Kp = FFP; W = W2; Wt = W2t;
    }

    __shared__ float T[64][65];
    const int n0 = bx * 64, k0 = by * 64;
    const int r = tid >> 4;            // 0..15
    const int c = (tid & 15) * 4;      // 0..60
    #pragma unroll
    for (int i = 0; i < 4; i++) {
        const int kk = k0 + r + i * 16;
        #pragma unroll
        for (int e = 0; e < 4; e++) {
            const int nn = n0 + c + e;
            T[r + i * 16][c + e] = (kk < K && nn < N) ? W[(size_t)kk * N + nn] : 0.0f;
        }
    }
    __syncthreads();
    #pragma unroll
    for (int i = 0; i < 4; i++) {
        const int nn = r + i * 16;
        ushort4 o;
        o.x = f2bf(T[c + 0][nn]);
        o.y = f2bf(T[c + 1][nn]);
        o.z = f2bf(T[c + 2][nn]);
        o.w = f2bf(T[c + 3][nn]);
        *(ushort4*)(Wt + (size_t)(n0 + nn) * Kp + k0 + c) = o;
    }
}
// note: W1t has 512 rows allocated; rows 500..511 get zeros (padding).

// ---------------------------------------------------------------------------
// Mask bit-pack: int32 0/1 [B,S,S] -> bitmask dwords [B,S,S/32]. Grid-stride.
// ---------------------------------------------------------------------------
__global__ void maskbits_kernel(const int* __restrict__ mask,
                                unsigned int* __restrict__ bits)
{
    const int lane = threadIdx.x & 63;
    const size_t stride = (size_t)gridDim.x * 256;
    const size_t total = (size_t)BATCH * SEQ * SEQ;
    for (size_t g = (size_t)blockIdx.x * 256 + threadIdx.x; g < total; g += stride) {
        const unsigned long long bal = __ballot(mask[g] != 0);
        if (lane == 0)  bits[g >> 5] = (unsigned int)bal;
        if (lane == 32) bits[g >> 5] = (unsigned int)(bal >> 32);
    }
}

// ---------------------------------------------------------------------------
// LayerNorm -> bf16. One block per row; wave-shuffle reduction, 1 barrier.
// ---------------------------------------------------------------------------
__global__ void ln_kernel(const float* __restrict__ x,
                          const float* __restrict__ alpha,
                          const float* __restrict__ bias,
                          ushortT* __restrict__ out)
{
    __shared__ float p1[4], p2[4];
    const int row = blockIdx.x;
    const int tid = threadIdx.x;
    const int wave = tid >> 6, lane = tid & 63;
    float4 v = ((const float4*)(x + (size_t)row * FEAT))[tid];

    float s1 = v.x + v.y + v.z + v.w;
    float s2 = v.x * v.x + v.y * v.y + v.z * v.z + v.w * v.w;
    #pragma unroll
    for (int off = 32; off > 0; off >>= 1) {
        s1 += __shfl_xor(s1, off);
        s2 += __shfl_xor(s2, off);
    }
    if (lane == 0) { p1[wave] = s1; p2[wave] = s2; }
    __syncthreads();
    const float t1 = p1[0] + p1[1] + p1[2] + p1[3];
    const float t2 = p2[0] + p2[1] + p2[2] + p2[3];
    const float mean = t1 * (1.0f / 1024.0f);
    const float var = fmaxf(t2 - 1024.0f * mean * mean, 0.0f) * (1.0f / 1023.0f);
    const float inv = 1.0f / (sqrtf(var) + 1e-6f);

    const float4 a = ((const float4*)alpha)[tid];
    const float4 b = ((const float4*)bias)[tid];
    ushort4 o;
    o.x = f2bf(a.x * (v.x - mean) * inv + b.x);
    o.y = f2bf(a.y * (v.y - mean) * inv + b.y);
    o.z = f2bf(a.z * (v.z - mean) * inv + b.z);
    o.w = f2bf(a.w * (v.w - mean) * inv + b.w);
    ((ushort4*)(out + (size_t)row * FEAT))[tid] = o;
}

// ---------------------------------------------------------------------------
// bf16 MFMA GEMM — 2-phase pipelined K-loop; BM x BN tiles.
// BM=128: 256 threads (4 waves). BM=256: 512 threads (8 waves, wm=wave>>1
// owns 64 rows, wn=wave&1 owns 64 cols; requires BN=128).
// Round-16: QKV moved to 256x128 -- LDS 48KB -> capacity 3/CU and grid
// 768 = exactly 3.0/CU (was 6/CU vs capacity 5 -> 17% tail), and staging
// arithmetic intensity +33% (128 MFMA / 24KB vs 64 / 16KB per plane).
// Numerics bit-identical (same K-plane accumulation order).
// XCD-chunked swizzle (T1), grids %8==0. VSPLIT=1 (QKV only): V-projection
// cols (>=2048) stored directly transposed into Vt.
// ---------------------------------------------------------------------------
template<int ACT, int RES, int OUT_BF16, int BM, int BN, int VSPLIT>
__global__ __launch_bounds__((BM == 256) ? 512 : 256)
void mfma_gemm(const ushortT* __restrict__ A, const ushortT* __restrict__ Bt,
               const float* __restrict__ bias, const float* __restrict__ R,
               void* __restrict__ Cout, ushortT* __restrict__ Vt,
               int M, int N, int K)
{
    constexpr int NWAVE = (BM == 256) ? 8 : 4;
    constexpr int MT = (BN == 128) ? 4 : 2;            // acc rows (x16)
    constexpr int MSPAN = (BM == 256) ? 64 : ((BN == 128) ? 64 : 32);
    __shared__ ushortT As[2][BM * 32];
    __shared__ ushortT Bs[2][BN * 32];

    const int tid  = threadIdx.x;
    const int wave = tid >> 6, lane = tid & 63;
    const int quad = lane >> 4, l16 = lane & 15;
    const int wm = (BM == 256) ? (wave >> 1) : ((BN == 128) ? (wave >> 1) : wave);
    const int wn = (BN == 128) ? (wave & 1) : 0;

    const int nbx = gridDim.x;
    int lid = blockIdx.y * nbx + blockIdx.x;
    const int cpx = (nbx * gridDim.y) >> 3;     // grid %8 == 0 for all launches
    lid = (lid & 7) * cpx + (lid >> 3);
    const int row0 = (lid / nbx) * BM, col0 = (lid % nbx) * BN;

    const floatx4 z4 = {0.f, 0.f, 0.f, 0.f};
    floatx4 acc[MT][4];
    #pragma unroll
    for (int i = 0; i < MT; i++)
        #pragma unroll
        for (int j = 0; j < 4; j++) acc[i][j] = z4;

    // per-wave staging geometry (row-major [BM][32] planes, 64B rows)
    const int sr = lane >> 2;           // +row within 16-row chunk
    const int sco = (lane & 3) * 8;     // bf16 col offset within 32-col row

#define STAGE(P, KO) {                                                        \
    _Pragma("unroll")                                                         \
    for (int i = 0; i < 2; i++) {                                             \
        const int rbase = 16 * (wave + NWAVE * i);                            \
        async16((char*)As[P] + rbase * 64,                                    \
                A + (size_t)(row0 + rbase + sr) * K + (KO) + sco);            \
    }                                                                         \
    if (BM == 256) {                                                          \
        const int rbase = 16 * wave;      /* 8 waves cover 128 B-rows */      \
        async16((char*)Bs[P] + rbase * 64,                                    \
                Bt + (size_t)(col0 + rbase + sr) * K + (KO) + sco);           \
    } else if (BN == 128) {                                                   \
        _Pragma("unroll")                                                     \
        for (int i = 0; i < 2; i++) {                                         \
            const int rbase = 16 * (wave + 4 * i);                            \
            async16((char*)Bs[P] + rbase * 64,                                \
                    Bt + (size_t)(col0 + rbase + sr) * K + (KO) + sco);       \
        }                                                                     \
    } else {                                                                  \
        const int rbase = 16 * wave;                                          \
        async16((char*)Bs[P] + rbase * 64,                                    \
                Bt + (size_t)(col0 + rbase + sr) * K + (KO) + sco);           \
    } }

    const int NK = K >> 5;              // number of 32-K planes
    STAGE(0, 0);                        // prologue: plane 0 in flight

    for (int ks = 0; ks < NK; ks++) {
        __syncthreads();                // implicit vmcnt(0): plane ks ready
        if (ks + 1 < NK) STAGE((ks + 1) & 1, (ks + 1) << 5);

        const int p = ks & 1;
        short8 af[MT], bf4[4];
        #pragma unroll
        for (int mt = 0; mt < MT; mt++)
            af[mt] = *(const short8*)&As[p][(MSPAN * wm + 16 * mt + l16) * 32 + quad * 8];
        #pragma unroll
        for (int nt = 0; nt < 4; nt++)
            bf4[nt] = *(const short8*)&Bs[p][(64 * wn + 16 * nt + l16) * 32 + quad * 8];
        #pragma unroll
        for (int mt = 0; mt < MT; mt++)
            #pragma unroll
            for (int nt = 0; nt < 4; nt++)
                acc[mt][nt] = __builtin_amdgcn_mfma_f32_16x16x32_bf16(
                    af[mt], bf4[nt], acc[mt][nt], 0, 0, 0);
    }
#undef STAGE

    #pragma unroll
    for (int mt = 0; mt < MT; mt++) {
        #pragma unroll
        for (int nt = 0; nt < 4; nt++) {
            const int col = col0 + 64 * wn + 16 * nt + l16;
            const int rbase = row0 + MSPAN * wm + 16 * mt + quad * 4;
            if (VSPLIT && col >= 2048) {
                // V projection -> transposed [b][hd][j] store, 4 j per thread
                const int bb = rbase >> 11;          // row / SEQ
                const int jj = rbase & 2047;         // row % SEQ
                const float bv = bias[col];
                ushort4 o4;
                o4.x = f2bf(acc[mt][nt][0] + bv);
                o4.y = f2bf(acc[mt][nt][1] + bv);
                o4.z = f2bf(acc[mt][nt][2] + bv);
                o4.w = f2bf(acc[mt][nt][3] + bv);
                *(ushort4*)(Vt + ((size_t)(bb * 1024 + (col - 2048))) * SEQ + jj) = o4;
                continue;
            }
            #pragma unroll
            for (int r = 0; r < 4; r++) {
                const int row = rbase + r;
                float val = acc[mt][nt][r] + bias[col];
                if (ACT == 1) val = (val > 0.0f) ? val : (__expf(val) - 1.0f);
                if (RES) val += R[(size_t)row * N + col];
                if (OUT_BF16)
                    ((ushortT*)Cout)[(size_t)row * N + col] = f2bf(val);
                else
                    ((float*)Cout)[(size_t)row * N + col] = val;
            }
        }
    }
}

// ---------------------------------------------------------------------------
// MFMA flash attention — round-6 configuration (session-best ~107-109us,
// reproduced rounds 10-15). 8 waves x 16 q-rows (AQ=128), dbuf K/V
// (1 barrier/tile), Ps-LDS P path, XCD block swizzle (FETCH 140->27MB),
// s_setprio around MFMA clusters, mask words prefetched one tile ahead.
// ---------------------------------------------------------------------------
__global__ __launch_bounds__(512)
void mfma_attn(const ushortT* __restrict__ qkv, const ushortT* __restrict__ vt,
               const unsigned int* __restrict__ mbits, ushortT* __restrict__ attn_out)
{
    __shared__ ushortT Ks[2][64 * 64];    // [j][d] swizzled
    __shared__ ushortT Vts[2][64 * 64];   // [d][j] swizzled
    __shared__ ushortT Ps[AQ * 64];       // [m][j] swizzled, wave-private rows

    const int tid = threadIdx.x;
    const int wave = tid >> 6, lane = tid & 63;   // wave 0..7
    const int quad = lane >> 4, l16 = lane & 15;
    // XCD-aware bijective swizzle (grid=1024, 1024%8==0): raw%8 = XCD.
    const int bid = ((blockIdx.x & 7) << 7) | (blockIdx.x >> 3);
    const int qt = bid & 15, h = (bid >> 4) & 15, b = bid >> 8;
    const int q0 = qt * AQ;

    const ushortT* qptr = qkv;
    const ushortT* kptr = qkv + 1024;

    // Q fragment: this wave owns rows q0 + 16*wave .. +15. Pre-scaled.
    short8 qf[2];
    {
        const size_t qrow = (size_t)(b * SEQ + q0 + 16 * wave + l16);
        short8 t0 = *(const short8*)(qptr + qrow * QKVSTR + h * 64 + quad * 8);
        short8 t1 = *(const short8*)(qptr + qrow * QKVSTR + h * 64 + 32 + quad * 8);
        const float cs = 0.125f * 1.4426950408889634f;
        #pragma unroll
        for (int i = 0; i < 8; i++) {
            qf[0][i] = (short)f2bf(bf2f(t0[i]) * cs);
            qf[1][i] = (short)f2bf(bf2f(t1[i]) * cs);
        }
    }

    short8 ones8;
    #pragma unroll
    for (int i = 0; i < 8; i++) ones8[i] = (short)0x3F80;  // bf16 1.0

    const floatx4 z4 = {0.f, 0.f, 0.f, 0.f};
    floatx4 o[4];
    #pragma unroll
    for (int dt = 0; dt < 4; dt++) o[dt] = z4;
    floatx4 lacc = z4;

    // staging: 512 threads, one K short8 + one V short8 each.
    const int rr = tid >> 3;            // 0..63 (row of K tile / d-row of V tile)
    const int c0 = tid & 7;             // 0..7 (16B chunk within row)
    const ushortT* gk = kptr + (size_t)(b * SEQ + rr) * QKVSTR + h * 64 + c0 * 8;
    const ushortT* gv = vt + ((size_t)((b * HEADS + h) * 64 + rr)) * SEQ + c0 * 8;
    short8 rk, rv;

#define ATTN_ISSUE() {                                                       \
    rk = *(const short8*)gk;                                                 \
    rv = *(const short8*)gv;                                                 \
    gk += (size_t)64 * QKVSTR; gv += 64; }

#define ATTN_WRITE(BI) {                                                     \
    *(short8*)&Ks[BI][rr * 64 + ((c0 ^ (rr & 7)) * 8)] = rk;                 \
    *(short8*)&Vts[BI][rr * 64 + ((c0 ^ (rr & 7)) * 8)] = rv; }

    const unsigned int* mrowp =
        mbits + (size_t)(b * SEQ + q0 + 16 * wave + l16) * (SEQ / 32);
    const int mloc = 16 * wave + l16;

    // Prologue: stage tile 0; preload mask words for tile 0.
    ATTN_ISSUE();
    ATTN_WRITE(0);
    unsigned int w0 = mrowp[0], w1 = mrowp[1];

    #pragma unroll 2
    for (int jt = 0; jt < 32; jt++) {
        __syncthreads();
        const int cur = jt & 1;
        unsigned int wn0 = 0, wn1 = 0;
        if (jt < 31) {
            ATTN_ISSUE();
            wn0 = mrowp[jt * 2 + 2];
            wn1 = mrowp[jt * 2 + 3];
        }

        // S^T = K @ Q^T
        floatx4 st[4];
        __builtin_amdgcn_s_setprio(1);
        #pragma unroll
        for (int nt = 0; nt < 4; nt++) {
            const int j = nt * 16 + l16;
            short8 ka0 = *(const short8*)&Ks[cur][j * 64 + ((quad ^ (j & 7)) * 8)];
            short8 ka1 = *(const short8*)&Ks[cur][j * 64 + (((4 + quad) ^ (j & 7)) * 8)];
            floatx4 t = z4;
            t = __builtin_amdgcn_mfma_f32_16x16x32_bf16(ka0, qf[0], t, 0, 0, 0);
            t = __builtin_amdgcn_mfma_f32_16x16x32_bf16(ka1, qf[1], t, 0, 0, 0);
            st[nt] = t;
        }
        __builtin_amdgcn_s_setprio(0);

        // softmax: p = exp2(masked ? 0 : s); packed bf16 writes into Ps[m][j]
        #pragma unroll
        for (int nt = 0; nt < 4; nt++) {
            const unsigned int ww = (nt & 2) ? w1 : w0;
            const unsigned int wsh = ww >> ((nt & 1) * 16 + quad * 4);
            float p[4];
            p[0] = EXP2F((wsh & 1u) ? st[nt][0] : 0.0f);
            p[1] = EXP2F((wsh & 2u) ? st[nt][1] : 0.0f);
            p[2] = EXP2F((wsh & 4u) ? st[nt][2] : 0.0f);
            p[3] = EXP2F((wsh & 8u) ? st[nt][3] : 0.0f);
            const int j0 = nt * 16 + quad * 4;
            const int chunk = (j0 >> 3) ^ (mloc & 7);
            const int ci = j0 & 7;
            ushortT* dst = &Ps[mloc * 64 + chunk * 8 + ci];
            *(__hip_bfloat162*)(dst)     = __float22bfloat162_rn(make_float2(p[0], p[1]));
            *(__hip_bfloat162*)(dst + 2) = __float22bfloat162_rn(make_float2(p[2], p[3]));
        }

        // O += P @ V ; lacc += P @ ones  (Ps rows wave-private: no barrier)
        short8 pa0 = *(const short8*)&Ps[mloc * 64 + ((quad ^ (mloc & 7)) * 8)];
        short8 pa1 = *(const short8*)&Ps[mloc * 64 + (((4 + quad) ^ (mloc & 7)) * 8)];
        lacc = __builtin_amdgcn_mfma_f32_16x16x32_bf16(pa0, ones8, lacc, 0, 0, 0);
        lacc = __builtin_amdgcn_mfma_f32_16x16x32_bf16(pa1, ones8, lacc, 0, 0, 0);
        __builtin_amdgcn_s_setprio(1);
        #pragma unroll
        for (int dt = 0; dt < 4; dt++) {
            const int d = dt * 16 + l16;
            short8 vb0 = *(const short8*)&Vts[cur][d * 64 + ((quad ^ (d & 7)) * 8)];
            short8 vb1 = *(const short8*)&Vts[cur][d * 64 + (((4 + quad) ^ (d & 7)) * 8)];
            o[dt] = __builtin_amdgcn_mfma_f32_16x16x32_bf16(pa0, vb0, o[dt], 0, 0, 0);
            o[dt] = __builtin_amdgcn_mfma_f32_16x16x32_bf16(pa1, vb1, o[dt], 0, 0, 0);
        }
        __builtin_amdgcn_s_setprio(0);

        if (jt < 31) {
            ATTN_WRITE(cur ^ 1);
            w0 = wn0; w1 = wn1;
        }
    }

    // Normalize + store bf16.
    #pragma unroll
    for (int r = 0; r < 4; r++) {
        const float inv_l = 1.0f / lacc[r];
        const size_t row = (size_t)(b * SEQ + q0 + 16 * wave + quad * 4 + r);
        #pragma unroll
        for (int dt = 0; dt < 4; dt++) {
            attn_out[row * FEAT + h * 64 + dt * 16 + l16] = f2bf(o[dt][r] * inv_l);
        }
    }
#undef ATTN_ISSUE
#undef ATTN_WRITE
}

// ---------------------------------------------------------------------------
// Launch
// ---------------------------------------------------------------------------
extern "C" void kernel_launch(void* const* d_in, const int* in_sizes, int n_in,
                              void* d_out, int out_size, void* d_ws, size_t ws_size,
                              hipStream_t stream)
{
    const float* x      = (const float*)d_in[0];
    const int*   mask   = (const int*)d_in[1];
    const float* alpha1 = (const float*)d_in[2];
    const float* bias1  = (const float*)d_in[3];
    const float* alpha2 = (const float*)d_in[4];
    const float* bias2  = (const float*)d_in[5];
    const float* Wq     = (const float*)d_in[6];
    const float* bq     = (const float*)d_in[7];
    const float* Wk     = (const float*)d_in[8];
    const float* bk     = (const float*)d_in[9];
    const float* Wv     = (const float*)d_in[10];
    const float* bv     = (const float*)d_in[11];
    const float* Wo     = (const float*)d_in[12];
    const float* bo     = (const float*)d_in[13];
    const float* W1     = (const float*)d_in[14];
    const float* b1     = (const float*)d_in[15];
    const float* W2     = (const float*)d_in[16];
    const float* b2     = (const float*)d_in[17];
    float* out = (float*)d_out;

    char* ws = (char*)d_ws;
    const size_t MB = 1024 * 1024;
    ushortT* x2b    = (ushortT*)(ws);              // LN1 out; attn out later
    ushortT* attn_o = (ushortT*)(ws);
    ushortT* qkv    = (ushortT*)(ws + 16 * MB);    // fused q|k|v (v region unused)
    ushortT* x2b2   = (ushortT*)(ws + 16 * MB);    // LN2 out (after attn)
    ushortT* hbuf   = (ushortT*)(ws + 32 * MB);    // FF hidden
    ushortT* vtb    = (ushortT*)(ws + 64 * MB);
    ushortT* Wqkvt  = (ushortT*)(ws + 80 * MB);    // 6 MB  [3072][1024]
    ushortT* Wot    = (ushortT*)(ws + 86 * MB);    // 2 MB
    ushortT* W1t    = (ushortT*)(ws + 88 * MB);    // 1 MB  [512][1024]
    ushortT* W2t    = (ushortT*)(ws + 89 * MB);    // 1 MB  [1024][512]
    float*   b1p    = (float*)  (ws + 90 * MB);
    float*   bqkv   = (float*)  (ws + 90 * MB + 16384);
    unsigned int* mbits = (unsigned int*)(ws + 91 * MB); // 2 MB

    const dim3 blk(256);

    // Prep (1 launch) + mask pack (grid-stride, 2048 blocks)
    prep_kernel<<<1281, blk, 0, stream>>>(Wq, Wk, Wv, Wo, W1, W2, bq, bk, bv, b1,
                                          Wqkvt, Wot, W1t, W2t, bqkv, b1p);
    maskbits_kernel<<<2048, blk, 0, stream>>>(mask, mbits);

    // 1. LN1 -> bf16
    ln_kernel<<<ROWS, blk, 0, stream>>>(x, alpha1, bias1, x2b);

    // 2. Fused QKV projection (256x128 tiles, 512 threads, 768 blocks =
    //    exactly 3/CU, zero tail); V written directly transposed into vtb.
    mfma_gemm<0, 0, 1, 256, 128, 1><<<dim3(24, 32), dim3(512), 0, stream>>>(
        x2b, Wqkvt, bqkv, nullptr, qkv, vtb, ROWS, QKVSTR, FEAT);

    // 3. Flash attention (512-thread blocks, AQ=128)
    mfma_attn<<<BATCH * HEADS * (SEQ / AQ), dim3(512), 0, stream>>>(qkv, vtb, mbits, attn_o);

    // 4. out = x + attn @ Wo + bo   (BN=64: 1024 blocks -> 4/CU)
    mfma_gemm<0, 1, 0, 128, 64, 0><<<dim3(16, 64), blk, 0, stream>>>(
        attn_o, Wot, bo, x, out, nullptr, ROWS, FEAT, FEAT);

    // 5. LN2 -> bf16
    ln_kernel<<<ROWS, blk, 0, stream>>>(out, alpha2, bias2, x2b2);

    // 6. h = ELU(x2b2 @ W1 + b1)
    mfma_gemm<1, 0, 1, 128, 64, 0><<<dim3(FFP / 64, 64), blk, 0, stream>>>(
        x2b2, W1t, b1p, nullptr, hbuf, nullptr, ROWS, FFP, FEAT);

    // 7. out += h @ W2 + b2         (BN=64: 1024 blocks -> 4/CU)
    mfma_gemm<0, 1, 0, 128, 64, 0><<<dim3(16, 64), blk, 0, stream>>>(
        hbuf, W2t, b2, out, out, nullptr, ROWS, FEAT, FFP);
}

// Round 17
// 430.131 us; speedup vs baseline: 1.0228x; 1.0228x over previous
//
#include <hip/hip_runtime.h>
#include <hip/hip_bf16.h>
#include <math.h>

// Problem constants
#define BATCH 4
#define SEQ 2048
#define FEAT 1024
#define HEADS 16
#define HDIM 64
#define FF 500
#define FFP 512                 // FF padded to multiple of 128
#define ROWS (BATCH * SEQ)      // 8192
#define QKVSTR 3072             // fused q|k|v row stride
#define AQ 128                  // attn q-rows per block (8 waves x 16 rows)

typedef unsigned short ushortT;
typedef __attribute__((ext_vector_type(8))) short short8;   // 8 bf16 (4 VGPRs)
typedef __attribute__((ext_vector_type(4))) float floatx4;  // MFMA acc

#if defined(__has_builtin) && __has_builtin(__builtin_amdgcn_exp2f)
#define EXP2F(x) __builtin_amdgcn_exp2f(x)
#else
#define EXP2F(x) exp2f(x)
#endif

__device__ __forceinline__ unsigned short f2bf(float f) {
    unsigned int u = __builtin_bit_cast(unsigned int, f);
    u += 0x7fffu + ((u >> 16) & 1u);           // RNE
    return (unsigned short)(u >> 16);
}
__device__ __forceinline__ float bf2f(short b) {
    unsigned int u = ((unsigned int)(unsigned short)b) << 16;
    return __builtin_bit_cast(float, u);
}

__device__ __forceinline__ void async16(void* lds, const void* g) {
    __builtin_amdgcn_global_load_lds(
        (const __attribute__((address_space(1))) unsigned int*)g,
        (__attribute__((address_space(3))) unsigned int*)lds, 16, 0, 0);
}

// ---------------------------------------------------------------------------
// Unified prep: 6 weight transpose+convert tiles + bias concat/pad.
// ---------------------------------------------------------------------------
__global__ void prep_kernel(const float* __restrict__ Wq, const float* __restrict__ Wk,
                            const float* __restrict__ Wv, const float* __restrict__ Wo,
                            const float* __restrict__ W1, const float* __restrict__ W2,
                            const float* __restrict__ bq, const float* __restrict__ bk,
                            const float* __restrict__ bv, const float* __restrict__ b1,
                            ushortT* __restrict__ Wqkvt, ushortT* __restrict__ Wot,
                            ushortT* __restrict__ W1t, ushortT* __restrict__ W2t,
                            float* __restrict__ bqkv, float* __restrict__ b1p)
{
    const int t = blockIdx.x;
    const int tid = threadIdx.x;
    if (t == 1280) {
        for (int i = tid; i < QKVSTR; i += 256)
            bqkv[i] = (i < 1024) ? bq[i] : ((i < 2048) ? bk[i - 1024] : bv[i - 2048]);
        for (int i = tid; i < FFP; i += 256)
            b1p[i] = (i < FF) ? b1[i] : 0.0f;
        return;
    }
    const float* W; ushortT* Wt; int K, N, Kp, bx, by;
    if (t < 1024) {
        const int wi = t >> 8, lt = t & 255;
        bx = lt & 15; by = lt >> 4; K = FEAT; N = FEAT; Kp = FEAT;
        W  = (wi == 0) ? Wq : (wi == 1) ? Wk : (wi == 2) ? Wv : Wo;
        Wt = (wi == 3) ? Wot : (Wqkvt + (size_t)wi * FEAT * FEAT);
    } else if (t < 1152) {
        const int lt = t - 1024; bx = lt & 7; by = lt >> 3;
        K = FEAT; N = FF; Kp = FEAT; W = W1; Wt = W1t;
    } else {
        const int lt = t - 1152; bx = lt & 15; by = lt >> 4;
        K = FF; N = FEAT; Kp = FFP; W = W2; Wt = W2t;
    }

    __shared__ float T[64][65];
    const int n0 = bx * 64, k0 = by * 64;
    const int r = tid >> 4;            // 0..15
    const int c = (tid & 15) * 4;      // 0..60
    #pragma unroll
    for (int i = 0; i < 4; i++) {
        const int kk = k0 + r + i * 16;
        #pragma unroll
        for (int e = 0; e < 4; e++) {
            const int nn = n0 + c + e;
            T[r + i * 16][c + e] = (kk < K && nn < N) ? W[(size_t)kk * N + nn] : 0.0f;
        }
    }
    __syncthreads();
    #pragma unroll
    for (int i = 0; i < 4; i++) {
        const int nn = r + i * 16;
        ushort4 o;
        o.x = f2bf(T[c + 0][nn]);
        o.y = f2bf(T[c + 1][nn]);
        o.z = f2bf(T[c + 2][nn]);
        o.w = f2bf(T[c + 3][nn]);
        *(ushort4*)(Wt + (size_t)(n0 + nn) * Kp + k0 + c) = o;
    }
}
// note: W1t has 512 rows allocated; rows 500..511 get zeros (padding).

// ---------------------------------------------------------------------------
// Mask bit-pack: int32 0/1 [B,S,S] -> bitmask dwords [B,S,S/32]. Grid-stride.
// ---------------------------------------------------------------------------
__global__ void maskbits_kernel(const int* __restrict__ mask,
                                unsigned int* __restrict__ bits)
{
    const int lane = threadIdx.x & 63;
    const size_t stride = (size_t)gridDim.x * 256;
    const size_t total = (size_t)BATCH * SEQ * SEQ;
    for (size_t g = (size_t)blockIdx.x * 256 + threadIdx.x; g < total; g += stride) {
        const unsigned long long bal = __ballot(mask[g] != 0);
        if (lane == 0)  bits[g >> 5] = (unsigned int)bal;
        if (lane == 32) bits[g >> 5] = (unsigned int)(bal >> 32);
    }
}

// ---------------------------------------------------------------------------
// LayerNorm -> bf16. One block per row; wave-shuffle reduction, 1 barrier.
// ---------------------------------------------------------------------------
__global__ void ln_kernel(const float* __restrict__ x,
                          const float* __restrict__ alpha,
                          const float* __restrict__ bias,
                          ushortT* __restrict__ out)
{
    __shared__ float p1[4], p2[4];
    const int row = blockIdx.x;
    const int tid = threadIdx.x;
    const int wave = tid >> 6, lane = tid & 63;
    float4 v = ((const float4*)(x + (size_t)row * FEAT))[tid];

    float s1 = v.x + v.y + v.z + v.w;
    float s2 = v.x * v.x + v.y * v.y + v.z * v.z + v.w * v.w;
    #pragma unroll
    for (int off = 32; off > 0; off >>= 1) {
        s1 += __shfl_xor(s1, off);
        s2 += __shfl_xor(s2, off);
    }
    if (lane == 0) { p1[wave] = s1; p2[wave] = s2; }
    __syncthreads();
    const float t1 = p1[0] + p1[1] + p1[2] + p1[3];
    const float t2 = p2[0] + p2[1] + p2[2] + p2[3];
    const float mean = t1 * (1.0f / 1024.0f);
    const float var = fmaxf(t2 - 1024.0f * mean * mean, 0.0f) * (1.0f / 1023.0f);
    const float inv = 1.0f / (sqrtf(var) + 1e-6f);

    const float4 a = ((const float4*)alpha)[tid];
    const float4 b = ((const float4*)bias)[tid];
    ushort4 o;
    o.x = f2bf(a.x * (v.x - mean) * inv + b.x);
    o.y = f2bf(a.y * (v.y - mean) * inv + b.y);
    o.z = f2bf(a.z * (v.z - mean) * inv + b.z);
    o.w = f2bf(a.w * (v.w - mean) * inv + b.w);
    ((ushort4*)(out + (size_t)row * FEAT))[tid] = o;
}

// ---------------------------------------------------------------------------
// bf16 MFMA GEMM — 2-phase pipelined K-loop (T3 minimum-2-phase). 128xBN
// tile. BN=128: 2x2 waves, 4x4 frags; BN=64: 4x1 waves, 2x4 frags.
// Round-16 lesson (3rd occurrence): bigger tiles at fewer blocks/CU LOSE on
// this latency-dominated workload -- QKV at 256x128 (3 blocks/CU) regressed
// 8us vs 128x128 (6 blocks/CU). Block-level TLP > per-block efficiency.
// XCD-chunked swizzle (T1), grids %8==0. VSPLIT=1 (QKV only): V-projection
// cols (>=2048) stored directly transposed into Vt (replaces transpose_v).
// ---------------------------------------------------------------------------
template<int ACT, int RES, int OUT_BF16, int BN, int VSPLIT>
__global__ __launch_bounds__(256)
void mfma_gemm(const ushortT* __restrict__ A, const ushortT* __restrict__ Bt,
               const float* __restrict__ bias, const float* __restrict__ R,
               void* __restrict__ Cout, ushortT* __restrict__ Vt,
               int M, int N, int K)
{
    constexpr int MT = (BN == 128) ? 4 : 2;
    constexpr int MSPAN = (BN == 128) ? 64 : 32;
    __shared__ ushortT As[2][128 * 32];
    __shared__ ushortT Bs[2][BN * 32];

    const int tid  = threadIdx.x;
    const int wave = tid >> 6, lane = tid & 63;
    const int quad = lane >> 4, l16 = lane & 15;
    const int wm = (BN == 128) ? (wave >> 1) : wave;
    const int wn = (BN == 128) ? (wave & 1) : 0;

    const int nbx = gridDim.x;
    int lid = blockIdx.y * nbx + blockIdx.x;
    const int cpx = (nbx * gridDim.y) >> 3;     // grid %8 == 0 for all launches
    lid = (lid & 7) * cpx + (lid >> 3);
    const int row0 = (lid / nbx) * 128, col0 = (lid % nbx) * BN;

    const floatx4 z4 = {0.f, 0.f, 0.f, 0.f};
    floatx4 acc[MT][4];
    #pragma unroll
    for (int i = 0; i < MT; i++)
        #pragma unroll
        for (int j = 0; j < 4; j++) acc[i][j] = z4;

    // per-wave staging geometry (row-major [128][32] planes, 64B rows)
    const int sr = lane >> 2;           // +row within 16-row chunk
    const int sco = (lane & 3) * 8;     // bf16 col offset within 32-col row

#define STAGE(P, KO) {                                                        \
    _Pragma("unroll")                                                         \
    for (int i = 0; i < 2; i++) {                                             \
        const int rbase = 16 * (wave + 4 * i);                                \
        async16((char*)As[P] + rbase * 64,                                    \
                A + (size_t)(row0 + rbase + sr) * K + (KO) + sco);            \
    }                                                                         \
    if (BN == 128) {                                                          \
        _Pragma("unroll")                                                     \
        for (int i = 0; i < 2; i++) {                                         \
            const int rbase = 16 * (wave + 4 * i);                            \
            async16((char*)Bs[P] + rbase * 64,                                \
                    Bt + (size_t)(col0 + rbase + sr) * K + (KO) + sco);       \
        }                                                                     \
    } else {                                                                  \
        const int rbase = 16 * wave;                                          \
        async16((char*)Bs[P] + rbase * 64,                                    \
                Bt + (size_t)(col0 + rbase + sr) * K + (KO) + sco);           \
    } }

    const int NK = K >> 5;              // number of 32-K planes
    STAGE(0, 0);                        // prologue: plane 0 in flight

    for (int ks = 0; ks < NK; ks++) {
        __syncthreads();                // implicit vmcnt(0): plane ks ready
        if (ks + 1 < NK) STAGE((ks + 1) & 1, (ks + 1) << 5);

        const int p = ks & 1;
        short8 af[MT], bf4[4];
        #pragma unroll
        for (int mt = 0; mt < MT; mt++)
            af[mt] = *(const short8*)&As[p][(MSPAN * wm + 16 * mt + l16) * 32 + quad * 8];
        #pragma unroll
        for (int nt = 0; nt < 4; nt++)
            bf4[nt] = *(const short8*)&Bs[p][(64 * wn + 16 * nt + l16) * 32 + quad * 8];
        #pragma unroll
        for (int mt = 0; mt < MT; mt++)
            #pragma unroll
            for (int nt = 0; nt < 4; nt++)
                acc[mt][nt] = __builtin_amdgcn_mfma_f32_16x16x32_bf16(
                    af[mt], bf4[nt], acc[mt][nt], 0, 0, 0);
    }
#undef STAGE

    #pragma unroll
    for (int mt = 0; mt < MT; mt++) {
        #pragma unroll
        for (int nt = 0; nt < 4; nt++) {
            const int col = col0 + 64 * wn + 16 * nt + l16;
            const int rbase = row0 + MSPAN * wm + 16 * mt + quad * 4;
            if (VSPLIT && col >= 2048) {
                // V projection -> transposed [b][hd][j] store, 4 j per thread
                const int bb = rbase >> 11;          // row / SEQ
                const int jj = rbase & 2047;         // row % SEQ
                const float bv = bias[col];
                ushort4 o4;
                o4.x = f2bf(acc[mt][nt][0] + bv);
                o4.y = f2bf(acc[mt][nt][1] + bv);
                o4.z = f2bf(acc[mt][nt][2] + bv);
                o4.w = f2bf(acc[mt][nt][3] + bv);
                *(ushort4*)(Vt + ((size_t)(bb * 1024 + (col - 2048))) * SEQ + jj) = o4;
                continue;
            }
            #pragma unroll
            for (int r = 0; r < 4; r++) {
                const int row = rbase + r;
                float val = acc[mt][nt][r] + bias[col];
                if (ACT == 1) val = (val > 0.0f) ? val : (__expf(val) - 1.0f);
                if (RES) val += R[(size_t)row * N + col];
                if (OUT_BF16)
                    ((ushortT*)Cout)[(size_t)row * N + col] = f2bf(val);
                else
                    ((float*)Cout)[(size_t)row * N + col] = val;
            }
        }
    }
}

// ---------------------------------------------------------------------------
// MFMA flash attention — round-6 configuration (session-best ~107-109us,
// reproduced rounds 10-15). 8 waves x 16 q-rows (AQ=128), dbuf K/V
// (1 barrier/tile), Ps-LDS P path, XCD block swizzle (FETCH 140->27MB),
// s_setprio around MFMA clusters, mask words prefetched one tile ahead.
// ---------------------------------------------------------------------------
__global__ __launch_bounds__(512)
void mfma_attn(const ushortT* __restrict__ qkv, const ushortT* __restrict__ vt,
               const unsigned int* __restrict__ mbits, ushortT* __restrict__ attn_out)
{
    __shared__ ushortT Ks[2][64 * 64];    // [j][d] swizzled
    __shared__ ushortT Vts[2][64 * 64];   // [d][j] swizzled
    __shared__ ushortT Ps[AQ * 64];       // [m][j] swizzled, wave-private rows

    const int tid = threadIdx.x;
    const int wave = tid >> 6, lane = tid & 63;   // wave 0..7
    const int quad = lane >> 4, l16 = lane & 15;
    // XCD-aware bijective swizzle (grid=1024, 1024%8==0): raw%8 = XCD.
    const int bid = ((blockIdx.x & 7) << 7) | (blockIdx.x >> 3);
    const int qt = bid & 15, h = (bid >> 4) & 15, b = bid >> 8;
    const int q0 = qt * AQ;

    const ushortT* qptr = qkv;
    const ushortT* kptr = qkv + 1024;

    // Q fragment: this wave owns rows q0 + 16*wave .. +15. Pre-scaled.
    short8 qf[2];
    {
        const size_t qrow = (size_t)(b * SEQ + q0 + 16 * wave + l16);
        short8 t0 = *(const short8*)(qptr + qrow * QKVSTR + h * 64 + quad * 8);
        short8 t1 = *(const short8*)(qptr + qrow * QKVSTR + h * 64 + 32 + quad * 8);
        const float cs = 0.125f * 1.4426950408889634f;
        #pragma unroll
        for (int i = 0; i < 8; i++) {
            qf[0][i] = (short)f2bf(bf2f(t0[i]) * cs);
            qf[1][i] = (short)f2bf(bf2f(t1[i]) * cs);
        }
    }

    short8 ones8;
    #pragma unroll
    for (int i = 0; i < 8; i++) ones8[i] = (short)0x3F80;  // bf16 1.0

    const floatx4 z4 = {0.f, 0.f, 0.f, 0.f};
    floatx4 o[4];
    #pragma unroll
    for (int dt = 0; dt < 4; dt++) o[dt] = z4;
    floatx4 lacc = z4;

    // staging: 512 threads, one K short8 + one V short8 each.
    const int rr = tid >> 3;            // 0..63 (row of K tile / d-row of V tile)
    const int c0 = tid & 7;             // 0..7 (16B chunk within row)
    const ushortT* gk = kptr + (size_t)(b * SEQ + rr) * QKVSTR + h * 64 + c0 * 8;
    const ushortT* gv = vt + ((size_t)((b * HEADS + h) * 64 + rr)) * SEQ + c0 * 8;
    short8 rk, rv;

#define ATTN_ISSUE() {                                                       \
    rk = *(const short8*)gk;                                                 \
    rv = *(const short8*)gv;                                                 \
    gk += (size_t)64 * QKVSTR; gv += 64; }

#define ATTN_WRITE(BI) {                                                     \
    *(short8*)&Ks[BI][rr * 64 + ((c0 ^ (rr & 7)) * 8)] = rk;                 \
    *(short8*)&Vts[BI][rr * 64 + ((c0 ^ (rr & 7)) * 8)] = rv; }

    const unsigned int* mrowp =
        mbits + (size_t)(b * SEQ + q0 + 16 * wave + l16) * (SEQ / 32);
    const int mloc = 16 * wave + l16;

    // Prologue: stage tile 0; preload mask words for tile 0.
    ATTN_ISSUE();
    ATTN_WRITE(0);
    unsigned int w0 = mrowp[0], w1 = mrowp[1];

    #pragma unroll 2
    for (int jt = 0; jt < 32; jt++) {
        __syncthreads();
        const int cur = jt & 1;
        unsigned int wn0 = 0, wn1 = 0;
        if (jt < 31) {
            ATTN_ISSUE();
            wn0 = mrowp[jt * 2 + 2];
            wn1 = mrowp[jt * 2 + 3];
        }

        // S^T = K @ Q^T
        floatx4 st[4];
        __builtin_amdgcn_s_setprio(1);
        #pragma unroll
        for (int nt = 0; nt < 4; nt++) {
            const int j = nt * 16 + l16;
            short8 ka0 = *(const short8*)&Ks[cur][j * 64 + ((quad ^ (j & 7)) * 8)];
            short8 ka1 = *(const short8*)&Ks[cur][j * 64 + (((4 + quad) ^ (j & 7)) * 8)];
            floatx4 t = z4;
            t = __builtin_amdgcn_mfma_f32_16x16x32_bf16(ka0, qf[0], t, 0, 0, 0);
            t = __builtin_amdgcn_mfma_f32_16x16x32_bf16(ka1, qf[1], t, 0, 0, 0);
            st[nt] = t;
        }
        __builtin_amdgcn_s_setprio(0);

        // softmax: p = exp2(masked ? 0 : s); packed bf16 writes into Ps[m][j]
        #pragma unroll
        for (int nt = 0; nt < 4; nt++) {
            const unsigned int ww = (nt & 2) ? w1 : w0;
            const unsigned int wsh = ww >> ((nt & 1) * 16 + quad * 4);
            float p[4];
            p[0] = EXP2F((wsh & 1u) ? st[nt][0] : 0.0f);
            p[1] = EXP2F((wsh & 2u) ? st[nt][1] : 0.0f);
            p[2] = EXP2F((wsh & 4u) ? st[nt][2] : 0.0f);
            p[3] = EXP2F((wsh & 8u) ? st[nt][3] : 0.0f);
            const int j0 = nt * 16 + quad * 4;
            const int chunk = (j0 >> 3) ^ (mloc & 7);
            const int ci = j0 & 7;
            ushortT* dst = &Ps[mloc * 64 + chunk * 8 + ci];
            *(__hip_bfloat162*)(dst)     = __float22bfloat162_rn(make_float2(p[0], p[1]));
            *(__hip_bfloat162*)(dst + 2) = __float22bfloat162_rn(make_float2(p[2], p[3]));
        }

        // O += P @ V ; lacc += P @ ones  (Ps rows wave-private: no barrier)
        short8 pa0 = *(const short8*)&Ps[mloc * 64 + ((quad ^ (mloc & 7)) * 8)];
        short8 pa1 = *(const short8*)&Ps[mloc * 64 + (((4 + quad) ^ (mloc & 7)) * 8)];
        lacc = __builtin_amdgcn_mfma_f32_16x16x32_bf16(pa0, ones8, lacc, 0, 0, 0);
        lacc = __builtin_amdgcn_mfma_f32_16x16x32_bf16(pa1, ones8, lacc, 0, 0, 0);
        __builtin_amdgcn_s_setprio(1);
        #pragma unroll
        for (int dt = 0; dt < 4; dt++) {
            const int d = dt * 16 + l16;
            short8 vb0 = *(const short8*)&Vts[cur][d * 64 + ((quad ^ (d & 7)) * 8)];
            short8 vb1 = *(const short8*)&Vts[cur][d * 64 + (((4 + quad) ^ (d & 7)) * 8)];
            o[dt] = __builtin_amdgcn_mfma_f32_16x16x32_bf16(pa0, vb0, o[dt], 0, 0, 0);
            o[dt] = __builtin_amdgcn_mfma_f32_16x16x32_bf16(pa1, vb1, o[dt], 0, 0, 0);
        }
        __builtin_amdgcn_s_setprio(0);

        if (jt < 31) {
            ATTN_WRITE(cur ^ 1);
            w0 = wn0; w1 = wn1;
        }
    }

    // Normalize + store bf16.
    #pragma unroll
    for (int r = 0; r < 4; r++) {
        const float inv_l = 1.0f / lacc[r];
        const size_t row = (size_t)(b * SEQ + q0 + 16 * wave + quad * 4 + r);
        #pragma unroll
        for (int dt = 0; dt < 4; dt++) {
            attn_out[row * FEAT + h * 64 + dt * 16 + l16] = f2bf(o[dt][r] * inv_l);
        }
    }
#undef ATTN_ISSUE
#undef ATTN_WRITE
}

// ---------------------------------------------------------------------------
// Launch
// ---------------------------------------------------------------------------
extern "C" void kernel_launch(void* const* d_in, const int* in_sizes, int n_in,
                              void* d_out, int out_size, void* d_ws, size_t ws_size,
                              hipStream_t stream)
{
    const float* x      = (const float*)d_in[0];
    const int*   mask   = (const int*)d_in[1];
    const float* alpha1 = (const float*)d_in[2];
    const float* bias1  = (const float*)d_in[3];
    const float* alpha2 = (const float*)d_in[4];
    const float* bias2  = (const float*)d_in[5];
    const float* Wq     = (const float*)d_in[6];
    const float* bq     = (const float*)d_in[7];
    const float* Wk     = (const float*)d_in[8];
    const float* bk     = (const float*)d_in[9];
    const float* Wv     = (const float*)d_in[10];
    const float* bv     = (const float*)d_in[11];
    const float* Wo     = (const float*)d_in[12];
    const float* bo     = (const float*)d_in[13];
    const float* W1     = (const float*)d_in[14];
    const float* b1     = (const float*)d_in[15];
    const float* W2     = (const float*)d_in[16];
    const float* b2     = (const float*)d_in[17];
    float* out = (float*)d_out;

    char* ws = (char*)d_ws;
    const size_t MB = 1024 * 1024;
    ushortT* x2b    = (ushortT*)(ws);              // LN1 out; attn out later
    ushortT* attn_o = (ushortT*)(ws);
    ushortT* qkv    = (ushortT*)(ws + 16 * MB);    // fused q|k|v (v region unused)
    ushortT* x2b2   = (ushortT*)(ws + 16 * MB);    // LN2 out (after attn)
    ushortT* hbuf   = (ushortT*)(ws + 32 * MB);    // FF hidden
    ushortT* vtb    = (ushortT*)(ws + 64 * MB);
    ushortT* Wqkvt  = (ushortT*)(ws + 80 * MB);    // 6 MB  [3072][1024]
    ushortT* Wot    = (ushortT*)(ws + 86 * MB);    // 2 MB
    ushortT* W1t    = (ushortT*)(ws + 88 * MB);    // 1 MB  [512][1024]
    ushortT* W2t    = (ushortT*)(ws + 89 * MB);    // 1 MB  [1024][512]
    float*   b1p    = (float*)  (ws + 90 * MB);
    float*   bqkv   = (float*)  (ws + 90 * MB + 16384);
    unsigned int* mbits = (unsigned int*)(ws + 91 * MB); // 2 MB

    const dim3 blk(256);

    // Prep (1 launch) + mask pack (grid-stride, 2048 blocks)
    prep_kernel<<<1281, blk, 0, stream>>>(Wq, Wk, Wv, Wo, W1, W2, bq, bk, bv, b1,
                                          Wqkvt, Wot, W1t, W2t, bqkv, b1p);
    maskbits_kernel<<<2048, blk, 0, stream>>>(mask, mbits);

    // 1. LN1 -> bf16
    ln_kernel<<<ROWS, blk, 0, stream>>>(x, alpha1, bias1, x2b);

    // 2. Fused QKV projection (128x128, 1536 blocks = 6/CU); V written
    //    directly transposed into vtb (transpose_v kernel eliminated).
    mfma_gemm<0, 0, 1, 128, 1><<<dim3(24, 64), blk, 0, stream>>>(
        x2b, Wqkvt, bqkv, nullptr, qkv, vtb, ROWS, QKVSTR, FEAT);

    // 3. Flash attention (512-thread blocks, AQ=128)
    mfma_attn<<<BATCH * HEADS * (SEQ / AQ), dim3(512), 0, stream>>>(qkv, vtb, mbits, attn_o);

    // 4. out = x + attn @ Wo + bo   (BN=64: 1024 blocks -> 4/CU)
    mfma_gemm<0, 1, 0, 64, 0><<<dim3(16, 64), blk, 0, stream>>>(
        attn_o, Wot, bo, x, out, nullptr, ROWS, FEAT, FEAT);

    // 5. LN2 -> bf16
    ln_kernel<<<ROWS, blk, 0, stream>>>(out, alpha2, bias2, x2b2);

    // 6. h = ELU(x2b2 @ W1 + b1)
    mfma_gemm<1, 0, 1, 64, 0><<<dim3(FFP / 64, 64), blk, 0, stream>>>(
        x2b2, W1t, b1p, nullptr, hbuf, nullptr, ROWS, FFP, FEAT);

    // 7. out += h @ W2 + b2         (BN=64: 1024 blocks -> 4/CU)
    mfma_gemm<0, 1, 0, 64, 0><<<dim3(16, 64), blk, 0, stream>>>(
        hbuf, W2t, b2, out, out, nullptr, ROWS, FEAT, FFP);
}